// Round 18
// baseline (187.071 us; speedup 1.0000x reference)
//
#include <hip/hip_runtime.h>
#include <hip/hip_bf16.h>
#include <math.h>

#define NN 100000
#define NE 1600000
#define BSHIFT 8
#define NBUCK ((NN + (1 << BSHIFT) - 1) >> BSHIFT)   // 391
#define CAP 5120
#define BCHUNK 1536
#define BINGRID ((NE + BCHUNK - 1) / BCHUNK)         // 1042
#define G1GRID ((NN + 127) / 128)                    // 782
#define HROWS 128
#define NPW 8

typedef __attribute__((ext_vector_type(8))) short bf16x8;
typedef __attribute__((ext_vector_type(4))) float f32x4;

static __device__ inline unsigned short f2b(float f) {
    __hip_bfloat16 b = __float2bfloat16(f);
    return *reinterpret_cast<unsigned short*>(&b);
}

static __device__ inline bf16x8 pack8(float4 fa, float4 fb) {
    union { bf16x8 v; unsigned u[4]; } pk;
    pk.u[0] = (unsigned)f2b(fa.x) | ((unsigned)f2b(fa.y) << 16);
    pk.u[1] = (unsigned)f2b(fa.z) | ((unsigned)f2b(fa.w) << 16);
    pk.u[2] = (unsigned)f2b(fb.x) | ((unsigned)f2b(fb.y) << 16);
    pk.u[3] = (unsigned)f2b(fb.z) | ((unsigned)f2b(fb.w) << 16);
    return pk.v;
}

// ============ FUSED: gemm1 (MFMA, blocks 0..G1GRID) ∥ bin_edges (rest) ============
__global__ __launch_bounds__(256) void gemm1_bin(const float* __restrict__ x,
                                                 const float* __restrict__ W,
                                                 __hip_bfloat16* __restrict__ out,
                                                 const int* __restrict__ es,
                                                 const int* __restrict__ ed,
                                                 const float* __restrict__ ew,
                                                 int* __restrict__ bcur,
                                                 int2* __restrict__ srcdw) {
    __shared__ __align__(16) unsigned short Wt[64 * 136];    // 17408 B
    const int tid = threadIdx.x;
    if (blockIdx.x < G1GRID) {
        // ---------------- gemm1: x[N,128] @ W1[128,64] -> bf16 ----------------
        const int row0 = blockIdx.x * 128;
        for (int i = tid; i < 64 * 64; i += 256) {
            const int n = i & 63, kp = i >> 6;
            const unsigned pack = (unsigned)f2b(W[(2 * kp) * 64 + n]) |
                                  ((unsigned)f2b(W[(2 * kp + 1) * 64 + n]) << 16);
            *(unsigned*)&Wt[n * 136 + 2 * kp] = pack;
        }
        __syncthreads();
        const int l = tid & 63;
        const int wid = tid >> 6;
        const int m = l & 15, g = l >> 4;
        const int wr0 = wid * 32;
        f32x4 acc[2][4];
#pragma unroll
        for (int rt = 0; rt < 2; ++rt)
#pragma unroll
            for (int ct = 0; ct < 4; ++ct) acc[rt][ct] = 0;
#pragma unroll
        for (int ks = 0; ks < 4; ++ks) {
            bf16x8 a[2], b[4];
#pragma unroll
            for (int rt = 0; rt < 2; ++rt) {
                const int row = row0 + wr0 + rt * 16 + m;
                float4 fa = make_float4(0.f, 0.f, 0.f, 0.f), fb = fa;
                if (row < NN) {
                    const float* xr = x + (size_t)row * 128 + ks * 32 + g * 8;
                    fa = *(const float4*)xr;
                    fb = *(const float4*)(xr + 4);
                }
                a[rt] = pack8(fa, fb);
            }
#pragma unroll
            for (int ct = 0; ct < 4; ++ct)
                b[ct] = *(const bf16x8*)&Wt[(ct * 16 + m) * 136 + ks * 32 + g * 8];
#pragma unroll
            for (int rt = 0; rt < 2; ++rt)
#pragma unroll
                for (int ct = 0; ct < 4; ++ct)
                    acc[rt][ct] = __builtin_amdgcn_mfma_f32_16x16x32_bf16(a[rt], b[ct], acc[rt][ct], 0, 0, 0);
        }
#pragma unroll
        for (int rt = 0; rt < 2; ++rt)
#pragma unroll
            for (int ct = 0; ct < 4; ++ct)
#pragma unroll
                for (int j = 0; j < 4; ++j) {
                    const int r = row0 + wr0 + rt * 16 + g * 4 + j;
                    if (r < NN)
                        out[(size_t)r * 64 + ct * 16 + m] = __float2bfloat16(acc[rt][ct][j]);
                }
    } else {
        // ---------------- bin_edges: 256 threads, 6 edges/thread ----------------
        int* hist = (int*)Wt;
        int* base = hist + NBUCK;
        const int e0 = (blockIdx.x - G1GRID) * BCHUNK;
        for (int i = tid; i < NBUCK; i += 256) hist[i] = 0;
        __syncthreads();
        int d[6];
#pragma unroll
        for (int j = 0; j < 6; ++j) {
            const int e = e0 + j * 256 + tid;
            d[j] = (e < NE) ? ed[e] : -1;
            if (d[j] >= 0) atomicAdd(&hist[d[j] >> BSHIFT], 1);
        }
        __syncthreads();
        for (int i = tid; i < NBUCK; i += 256)
            base[i] = i * CAP + atomicAdd(&bcur[i], hist[i]);   // bcur holds relative counts
        __syncthreads();
        for (int i = tid; i < NBUCK; i += 256) hist[i] = 0;
        __syncthreads();
#pragma unroll
        for (int j = 0; j < 6; ++j) {
            const int e = e0 + j * 256 + tid;
            if (d[j] >= 0) {
                const int bb = d[j] >> BSHIFT;
                const int l2 = atomicAdd(&hist[bb], 1);
                srcdw[base[bb] + l2] =
                    make_int2(es[e] | ((d[j] & ((1 << BSHIFT) - 1)) << 17), __float_as_int(ew[e]));
            }
        }
    }
}

// ============ GEMM2 (MFMA): h[N,64] @ W2[64,64] -> out_bf16[N,64] ============
__global__ __launch_bounds__(256) void gemm2_mfma(const float* __restrict__ h,
                                                  const float* __restrict__ W,
                                                  __hip_bfloat16* __restrict__ out) {
    __shared__ __align__(16) unsigned short Wt[64 * 72];     // 9216 B
    const int tid = threadIdx.x;
    const int row0 = blockIdx.x * 128;
    for (int i = tid; i < 64 * 32; i += 256) {
        const int n = i & 63, kp = i >> 6;
        const unsigned pack = (unsigned)f2b(W[(2 * kp) * 64 + n]) |
                              ((unsigned)f2b(W[(2 * kp + 1) * 64 + n]) << 16);
        *(unsigned*)&Wt[n * 72 + 2 * kp] = pack;
    }
    __syncthreads();
    const int l = tid & 63;
    const int wid = tid >> 6;
    const int m = l & 15, g = l >> 4;
    const int wr0 = wid * 32;
    f32x4 acc[2][4];
#pragma unroll
    for (int rt = 0; rt < 2; ++rt)
#pragma unroll
        for (int ct = 0; ct < 4; ++ct) acc[rt][ct] = 0;
#pragma unroll
    for (int ks = 0; ks < 2; ++ks) {
        bf16x8 a[2], b[4];
#pragma unroll
        for (int rt = 0; rt < 2; ++rt) {
            const int row = row0 + wr0 + rt * 16 + m;
            float4 fa = make_float4(0.f, 0.f, 0.f, 0.f), fb = fa;
            if (row < NN) {
                const float* hr = h + (size_t)row * 64 + ks * 32 + g * 8;
                fa = *(const float4*)hr;
                fb = *(const float4*)(hr + 4);
            }
            a[rt] = pack8(fa, fb);
        }
#pragma unroll
        for (int ct = 0; ct < 4; ++ct)
            b[ct] = *(const bf16x8*)&Wt[(ct * 16 + m) * 72 + ks * 32 + g * 8];
#pragma unroll
        for (int rt = 0; rt < 2; ++rt)
#pragma unroll
            for (int ct = 0; ct < 4; ++ct)
                acc[rt][ct] = __builtin_amdgcn_mfma_f32_16x16x32_bf16(a[rt], b[ct], acc[rt][ct], 0, 0, 0);
    }
#pragma unroll
    for (int rt = 0; rt < 2; ++rt)
#pragma unroll
        for (int ct = 0; ct < 4; ++ct)
#pragma unroll
            for (int j = 0; j < 4; ++j) {
                const int r = row0 + wr0 + rt * 16 + g * 4 + j;
                if (r < NN)
                    out[(size_t)r * 64 + ct * 16 + m] = __float2bfloat16(acc[rt][ct][j]);
            }
}

// ---------------- per-bucket CSR finalize: 391 blocks x 512 threads ----------------
__global__ __launch_bounds__(512) void bucket_csr(const int2* __restrict__ srcdw,
                                                  const int* __restrict__ bcur,
                                                  int2* __restrict__ rng,
                                                  int2* __restrict__ edges2) {
    __shared__ int A[256], B2[256];
    const int tid = threadIdx.x;
    const int b = blockIdx.x;
    const int base = b * CAP;
    const int cnt = bcur[b];                   // relative count
    if (tid < 256) A[tid] = 0;
    __syncthreads();
    for (int e = tid; e < cnt; e += 512)
        atomicAdd(&A[(srcdw[base + e].x >> 17) & 255], 1);
    __syncthreads();
    const int v = (tid < 256) ? A[tid] : 0;
    int* src = A;
    int* dst = B2;
    for (int d = 1; d < 256; d <<= 1) {
        if (tid < 256) dst[tid] = src[tid] + ((tid >= d) ? src[tid - d] : 0);
        __syncthreads();
        int* t = src; src = dst; dst = t;
    }
    if (tid < 256) {
        const int incl = src[tid];
        const int excl = incl - v;
        const int node = (b << BSHIFT) + tid;
        if (node < NN) rng[node] = make_int2(base + excl, base + incl);
        dst[tid] = excl;
    }
    __syncthreads();
    for (int e = tid; e < cnt; e += 512) {
        const int2 sw = srcdw[base + e];
        const int dl = (sw.x >> 17) & 255;
        const int pos = atomicAdd(&dst[dl], 1);
        edges2[base + pos] = make_int2(sw.x & 0x1FFFF, sw.y);
    }
}

// ---------------- CSR SpMM: 8 nodes/wave, 8 edges per gather instr ----------------
__global__ __launch_bounds__(256) void spmm_csr(const __hip_bfloat16* __restrict__ feat,
                                                const int2* __restrict__ rng,
                                                const int2* __restrict__ edges2,
                                                const float* __restrict__ b,
                                                float* __restrict__ out) {
    const int nwg = gridDim.x;
    const int q = nwg >> 3, rr = nwg & 7;
    const int xcd = blockIdx.x & 7;
    const int sub = blockIdx.x >> 3;
    const int swz = (xcd < rr ? xcd * (q + 1) : rr * (q + 1) + (xcd - rr) * q) + sub;
    const int w = threadIdx.x >> 6;
    const int lane = threadIdx.x & 63;
    const int n0 = (swz * 4 + w) * NPW;
    const int p = lane >> 3;
    const int f8 = lane & 7;
    const float4 bv0 = *(const float4*)(b + f8 * 8);
    const float4 bv1 = *(const float4*)(b + f8 * 8 + 4);
    const int2 r8 = rng[n0 + f8];
#define FMA8(G, WV)                                            \
    a0 = fmaf(__uint_as_float((G).x << 16), (WV), a0);         \
    a1 = fmaf(__uint_as_float((G).x & 0xffff0000u), (WV), a1); \
    a2 = fmaf(__uint_as_float((G).y << 16), (WV), a2);         \
    a3 = fmaf(__uint_as_float((G).y & 0xffff0000u), (WV), a3); \
    a4 = fmaf(__uint_as_float((G).z << 16), (WV), a4);         \
    a5 = fmaf(__uint_as_float((G).z & 0xffff0000u), (WV), a5); \
    a6 = fmaf(__uint_as_float((G).w << 16), (WV), a6);         \
    a7 = fmaf(__uint_as_float((G).w & 0xffff0000u), (WV), a7);
#define RED(A) A += __shfl_xor(A, 8, 64); A += __shfl_xor(A, 16, 64); A += __shfl_xor(A, 32, 64);
#pragma unroll 1
    for (int nn = 0; nn < NPW; ++nn) {
        const int n = n0 + nn;
        const int beg = __shfl(r8.x, nn, 64);
        const int end = __shfl(r8.y, nn, 64);
        float a0 = 0.f, a1 = 0.f, a2 = 0.f, a3 = 0.f;
        float a4 = 0.f, a5 = 0.f, a6 = 0.f, a7 = 0.f;
        int i = beg;
        for (; i + 15 < end; i += 16) {
            const int2 e0 = edges2[i + p];
            const int2 e1 = edges2[i + 8 + p];
            const uint4 g0 = *(const uint4*)(feat + (size_t)e0.x * 64 + f8 * 8);
            const uint4 g1 = *(const uint4*)(feat + (size_t)e1.x * 64 + f8 * 8);
            const float w0 = __int_as_float(e0.y), w1 = __int_as_float(e1.y);
            FMA8(g0, w0) FMA8(g1, w1)
        }
        for (; i < end; i += 8) {
            const int idx = i + p;
            const int2 e = edges2[idx];
            const float wv = (idx < end) ? __int_as_float(e.y) : 0.f;
            const uint4 g = *(const uint4*)(feat + (size_t)(e.x & 0x1FFFF) * 64 + f8 * 8);
            FMA8(g, wv)
        }
        RED(a0) RED(a1) RED(a2) RED(a3) RED(a4) RED(a5) RED(a6) RED(a7)
        if (p == 0) {
            float4 o0, o1;
            o0.x = fmaxf(a0 + bv0.x, 0.f);
            o0.y = fmaxf(a1 + bv0.y, 0.f);
            o0.z = fmaxf(a2 + bv0.z, 0.f);
            o0.w = fmaxf(a3 + bv0.w, 0.f);
            o1.x = fmaxf(a4 + bv1.x, 0.f);
            o1.y = fmaxf(a5 + bv1.y, 0.f);
            o1.z = fmaxf(a6 + bv1.z, 0.f);
            o1.w = fmaxf(a7 + bv1.w, 0.f);
            *(float4*)(out + (size_t)n * 64 + f8 * 8) = o0;
            *(float4*)(out + (size_t)n * 64 + f8 * 8 + 4) = o1;
        }
    }
#undef FMA8
#undef RED
}

// ============ head: 128 rows x 40 cols per block, register-tiled ============
__global__ __launch_bounds__(256) void head_tile(const float* __restrict__ h2,
                                                 const float* __restrict__ Wl,
                                                 const float* __restrict__ bl,
                                                 float* __restrict__ logits,
                                                 float* __restrict__ logp) {
    __shared__ float Wt[40 * 68];
    __shared__ float Xs[HROWS * 68];
    __shared__ float bs[40];
    const int tid = threadIdx.x;
    const int row0 = blockIdx.x * HROWS;
    for (int i = tid; i < 64 * 40; i += 256) {
        const int k = i / 40, c = i - k * 40;
        Wt[c * 68 + k] = Wl[i];
    }
    if (tid < 40) bs[tid] = bl[tid];
    for (int i = tid; i < HROWS * 16; i += 256) {
        const int r = i >> 4, kq = i & 15;
        const int row = row0 + r;
        float4 v = make_float4(0.f, 0.f, 0.f, 0.f);
        if (row < NN) v = *(const float4*)(h2 + (size_t)row * 64 + kq * 4);
        *(float4*)(&Xs[r * 68 + kq * 4]) = v;
    }
    __syncthreads();
    const int tcol = tid & 3;
    const int trow = tid >> 2;
    float acc[2][10] = {};
    const float* xb0 = &Xs[trow * 68];
    const float* xb1 = &Xs[(trow + 64) * 68];
    const float* wb = &Wt[(tcol * 10) * 68];
    for (int k = 0; k < 64; k += 4) {
        const float4 x0 = *(const float4*)(xb0 + k);
        const float4 x1 = *(const float4*)(xb1 + k);
#pragma unroll
        for (int c = 0; c < 10; ++c) {
            const float4 wv = *(const float4*)(wb + c * 68 + k);
            acc[0][c] = fmaf(x0.x, wv.x, acc[0][c]);
            acc[0][c] = fmaf(x0.y, wv.y, acc[0][c]);
            acc[0][c] = fmaf(x0.z, wv.z, acc[0][c]);
            acc[0][c] = fmaf(x0.w, wv.w, acc[0][c]);
            acc[1][c] = fmaf(x1.x, wv.x, acc[1][c]);
            acc[1][c] = fmaf(x1.y, wv.y, acc[1][c]);
            acc[1][c] = fmaf(x1.z, wv.z, acc[1][c]);
            acc[1][c] = fmaf(x1.w, wv.w, acc[1][c]);
        }
    }
    float bv[10];
#pragma unroll
    for (int c = 0; c < 10; ++c) bv[c] = bs[tcol * 10 + c];
#pragma unroll
    for (int r = 0; r < 2; ++r) {
        const int row = row0 + trow + r * 64;
#pragma unroll
        for (int c = 0; c < 10; ++c) acc[r][c] += bv[c];
        float m = acc[r][0];
#pragma unroll
        for (int c = 1; c < 10; ++c) m = fmaxf(m, acc[r][c]);
        m = fmaxf(m, __shfl_xor(m, 1, 64));
        m = fmaxf(m, __shfl_xor(m, 2, 64));
        float s = 0.f;
#pragma unroll
        for (int c = 0; c < 10; ++c) s += expf(acc[r][c] - m);
        s += __shfl_xor(s, 1, 64);
        s += __shfl_xor(s, 2, 64);
        const float lse = logf(s) + m;
        if (row < NN) {
            float* lg = logits + (size_t)row * 40 + tcol * 10;
            float* lp = logp   + (size_t)row * 40 + tcol * 10;
#pragma unroll
            for (int c = 0; c < 10; c += 2) {
                *(float2*)(lg + c) = make_float2(acc[r][c], acc[r][c + 1]);
                *(float2*)(lp + c) = make_float2(acc[r][c] - lse, acc[r][c + 1] - lse);
            }
        }
    }
}

extern "C" void kernel_launch(void* const* d_in, const int* in_sizes, int n_in,
                              void* d_out, int out_size, void* d_ws, size_t ws_size,
                              hipStream_t stream) {
    const float* x  = (const float*)d_in[0];
    const int*   es = (const int*)  d_in[1];
    const int*   ed = (const int*)  d_in[2];
    const float* ew = (const float*)d_in[3];
    const float* W1 = (const float*)d_in[4];
    const float* b1 = (const float*)d_in[5];
    const float* W2 = (const float*)d_in[6];
    const float* b2 = (const float*)d_in[7];
    const float* Wl = (const float*)d_in[8];
    const float* bl = (const float*)d_in[9];

    float* out    = (float*)d_out;
    float* logp   = out;                          // [N,40]
    float* h1     = logp + (size_t)NN * 40;       // [N,64]
    float* h2     = h1   + (size_t)NN * 64;       // [N,64]
    float* logits = h2   + (size_t)NN * 64;       // [N,40]

    // workspace: NO overlay (ws0 written concurrently with srcdw in the fused kernel)
    char* wsb = (char*)d_ws;
    const size_t regionA = (size_t)NBUCK * CAP * 8;                   // ~15.3 MB
    int2* srcdw = (int2*)wsb;                                         // [NBUCK*CAP]
    int2* edges2 = (int2*)(wsb + regionA);                            // [NBUCK*CAP]
    int2* rng    = (int2*)((char*)edges2 + regionA);                  // [NN] 800 KB
    int*  bcur   = (int*)((char*)rng + (size_t)NN * 8);               // [NBUCK]
    __hip_bfloat16* ws0 = (__hip_bfloat16*)((char*)bcur + 4096);      // [N,64] bf16 12.8 MB

    const int gemmGrid = (NN + 127) / 128;        // 782
    const int spmmGrid = NN / (4 * NPW);          // 3125

    // ---- [gemm1 ∥ CSR binning] then per-bucket finalize ----
    hipMemsetAsync(bcur, 0, (size_t)NBUCK * 4, stream);
    gemm1_bin<<<G1GRID + BINGRID, 256, 0, stream>>>(x, W1, ws0, es, ed, ew, bcur, srcdw);
    bucket_csr<<<NBUCK, 512, 0, stream>>>(srcdw, bcur, rng, edges2);

    // ---- layer 1 aggregate ----
    spmm_csr<<<spmmGrid, 256, 0, stream>>>(ws0, rng, edges2, b1, h1);

    // ---- layer 2 ----
    gemm2_mfma<<<gemmGrid, 256, 0, stream>>>(h1, W2, ws0);
    spmm_csr<<<spmmGrid, 256, 0, stream>>>(ws0, rng, edges2, b2, h2);

    // ---- head ----
    head_tile<<<(NN + HROWS - 1) / HROWS, 256, 0, stream>>>(h2, Wl, bl, logits, logp);
}

// Round 19
// 184.126 us; speedup vs baseline: 1.0160x; 1.0160x over previous
//
#include <hip/hip_runtime.h>
#include <hip/hip_bf16.h>
#include <math.h>

#define NN 100000
#define NE 1600000
#define BSHIFT 9
#define NBUCK ((NN + (1 << BSHIFT) - 1) >> BSHIFT)   // 196
#define CAP 10240
#define BCHUNK 4096
#define BINGRID ((NE + BCHUNK - 1) / BCHUNK)         // 391
#define G1GRID ((NN + 127) / 128)                    // 782
#define HROWS 128
#define NPW 8

typedef __attribute__((ext_vector_type(8))) short bf16x8;
typedef __attribute__((ext_vector_type(4))) float f32x4;

static __device__ inline unsigned short f2b(float f) {
    __hip_bfloat16 b = __float2bfloat16(f);
    return *reinterpret_cast<unsigned short*>(&b);
}

static __device__ inline bf16x8 pack8(float4 fa, float4 fb) {
    union { bf16x8 v; unsigned u[4]; } pk;
    pk.u[0] = (unsigned)f2b(fa.x) | ((unsigned)f2b(fa.y) << 16);
    pk.u[1] = (unsigned)f2b(fa.z) | ((unsigned)f2b(fa.w) << 16);
    pk.u[2] = (unsigned)f2b(fb.x) | ((unsigned)f2b(fb.y) << 16);
    pk.u[3] = (unsigned)f2b(fb.z) | ((unsigned)f2b(fb.w) << 16);
    return pk.v;
}

// ============ FUSED: gemm1 (MFMA, blocks 0..G1GRID) ∥ bin_edges (rest) ============
// gemm1: W^T-only LDS (17.4 KB), A-fragments global->reg.
// bin: 4096-edge chunks -> ~21-edge (168 B) write runs per bucket (write-amp ~1.4x).
__global__ __launch_bounds__(256) void gemm1_bin(const float* __restrict__ x,
                                                 const float* __restrict__ W,
                                                 __hip_bfloat16* __restrict__ out,
                                                 const int* __restrict__ es,
                                                 const int* __restrict__ ed,
                                                 const float* __restrict__ ew,
                                                 int* __restrict__ bcur,
                                                 int2* __restrict__ srcdw) {
    __shared__ __align__(16) unsigned short Wt[64 * 136];    // 17408 B
    const int tid = threadIdx.x;
    if (blockIdx.x < G1GRID) {
        // ---------------- gemm1: x[N,128] @ W1[128,64] -> bf16 ----------------
        const int row0 = blockIdx.x * 128;
        for (int i = tid; i < 64 * 64; i += 256) {
            const int n = i & 63, kp = i >> 6;
            const unsigned pack = (unsigned)f2b(W[(2 * kp) * 64 + n]) |
                                  ((unsigned)f2b(W[(2 * kp + 1) * 64 + n]) << 16);
            *(unsigned*)&Wt[n * 136 + 2 * kp] = pack;
        }
        __syncthreads();
        const int l = tid & 63;
        const int wid = tid >> 6;
        const int m = l & 15, g = l >> 4;
        const int wr0 = wid * 32;
        f32x4 acc[2][4];
#pragma unroll
        for (int rt = 0; rt < 2; ++rt)
#pragma unroll
            for (int ct = 0; ct < 4; ++ct) acc[rt][ct] = 0;
#pragma unroll
        for (int ks = 0; ks < 4; ++ks) {
            bf16x8 a[2], b[4];
#pragma unroll
            for (int rt = 0; rt < 2; ++rt) {
                const int row = row0 + wr0 + rt * 16 + m;
                float4 fa = make_float4(0.f, 0.f, 0.f, 0.f), fb = fa;
                if (row < NN) {
                    const float* xr = x + (size_t)row * 128 + ks * 32 + g * 8;
                    fa = *(const float4*)xr;
                    fb = *(const float4*)(xr + 4);
                }
                a[rt] = pack8(fa, fb);
            }
#pragma unroll
            for (int ct = 0; ct < 4; ++ct)
                b[ct] = *(const bf16x8*)&Wt[(ct * 16 + m) * 136 + ks * 32 + g * 8];
#pragma unroll
            for (int rt = 0; rt < 2; ++rt)
#pragma unroll
                for (int ct = 0; ct < 4; ++ct)
                    acc[rt][ct] = __builtin_amdgcn_mfma_f32_16x16x32_bf16(a[rt], b[ct], acc[rt][ct], 0, 0, 0);
        }
#pragma unroll
        for (int rt = 0; rt < 2; ++rt)
#pragma unroll
            for (int ct = 0; ct < 4; ++ct)
#pragma unroll
                for (int j = 0; j < 4; ++j) {
                    const int r = row0 + wr0 + rt * 16 + g * 4 + j;
                    if (r < NN)
                        out[(size_t)r * 64 + ct * 16 + m] = __float2bfloat16(acc[rt][ct][j]);
                }
    } else {
        // ---------------- bin_edges: 256 threads, 16 edges/thread ----------------
        int* hist = (int*)Wt;
        int* base = hist + NBUCK;
        const int e0 = (blockIdx.x - G1GRID) * BCHUNK;
        for (int i = tid; i < NBUCK; i += 256) hist[i] = 0;
        __syncthreads();
        int d[16];
#pragma unroll
        for (int j = 0; j < 16; ++j) {
            const int e = e0 + j * 256 + tid;
            d[j] = (e < NE) ? ed[e] : -1;
            if (d[j] >= 0) atomicAdd(&hist[d[j] >> BSHIFT], 1);
        }
        __syncthreads();
        for (int i = tid; i < NBUCK; i += 256)
            base[i] = i * CAP + atomicAdd(&bcur[i], hist[i]);   // bcur holds relative counts
        __syncthreads();
        for (int i = tid; i < NBUCK; i += 256) hist[i] = 0;
        __syncthreads();
#pragma unroll
        for (int j = 0; j < 16; ++j) {
            const int e = e0 + j * 256 + tid;
            if (d[j] >= 0) {
                const int bb = d[j] >> BSHIFT;
                const int l2 = atomicAdd(&hist[bb], 1);
                srcdw[base[bb] + l2] =
                    make_int2(es[e] | ((d[j] & 511) << 17), __float_as_int(ew[e]));
            }
        }
    }
}

// ============ GEMM2 (MFMA): h[N,64] @ W2[64,64] -> out_bf16[N,64] ============
__global__ __launch_bounds__(256) void gemm2_mfma(const float* __restrict__ h,
                                                  const float* __restrict__ W,
                                                  __hip_bfloat16* __restrict__ out) {
    __shared__ __align__(16) unsigned short Wt[64 * 72];     // 9216 B
    const int tid = threadIdx.x;
    const int row0 = blockIdx.x * 128;
    for (int i = tid; i < 64 * 32; i += 256) {
        const int n = i & 63, kp = i >> 6;
        const unsigned pack = (unsigned)f2b(W[(2 * kp) * 64 + n]) |
                              ((unsigned)f2b(W[(2 * kp + 1) * 64 + n]) << 16);
        *(unsigned*)&Wt[n * 72 + 2 * kp] = pack;
    }
    __syncthreads();
    const int l = tid & 63;
    const int wid = tid >> 6;
    const int m = l & 15, g = l >> 4;
    const int wr0 = wid * 32;
    f32x4 acc[2][4];
#pragma unroll
    for (int rt = 0; rt < 2; ++rt)
#pragma unroll
        for (int ct = 0; ct < 4; ++ct) acc[rt][ct] = 0;
#pragma unroll
    for (int ks = 0; ks < 2; ++ks) {
        bf16x8 a[2], b[4];
#pragma unroll
        for (int rt = 0; rt < 2; ++rt) {
            const int row = row0 + wr0 + rt * 16 + m;
            float4 fa = make_float4(0.f, 0.f, 0.f, 0.f), fb = fa;
            if (row < NN) {
                const float* hr = h + (size_t)row * 64 + ks * 32 + g * 8;
                fa = *(const float4*)hr;
                fb = *(const float4*)(hr + 4);
            }
            a[rt] = pack8(fa, fb);
        }
#pragma unroll
        for (int ct = 0; ct < 4; ++ct)
            b[ct] = *(const bf16x8*)&Wt[(ct * 16 + m) * 72 + ks * 32 + g * 8];
#pragma unroll
        for (int rt = 0; rt < 2; ++rt)
#pragma unroll
            for (int ct = 0; ct < 4; ++ct)
                acc[rt][ct] = __builtin_amdgcn_mfma_f32_16x16x32_bf16(a[rt], b[ct], acc[rt][ct], 0, 0, 0);
    }
#pragma unroll
    for (int rt = 0; rt < 2; ++rt)
#pragma unroll
        for (int ct = 0; ct < 4; ++ct)
#pragma unroll
            for (int j = 0; j < 4; ++j) {
                const int r = row0 + wr0 + rt * 16 + g * 4 + j;
                if (r < NN)
                    out[(size_t)r * 64 + ct * 16 + m] = __float2bfloat16(acc[rt][ct][j]);
            }
}

// ---------------- per-bucket CSR finalize (1024 threads) ----------------
__global__ __launch_bounds__(1024) void bucket_csr(const int2* __restrict__ srcdw,
                                                   const int* __restrict__ bcur,
                                                   int2* __restrict__ rng,
                                                   int2* __restrict__ edges2) {
    __shared__ int A[512], B2[512];
    const int tid = threadIdx.x;
    const int b = blockIdx.x;
    const int base = b * CAP;
    const int cnt = bcur[b];                   // relative count
    if (tid < 512) A[tid] = 0;
    __syncthreads();
    for (int e = tid; e < cnt; e += 1024)
        atomicAdd(&A[(srcdw[base + e].x >> 17) & 511], 1);
    __syncthreads();
    const int v = (tid < 512) ? A[tid] : 0;
    int* src = A;
    int* dst = B2;
    for (int d = 1; d < 512; d <<= 1) {
        if (tid < 512) dst[tid] = src[tid] + ((tid >= d) ? src[tid - d] : 0);
        __syncthreads();
        int* t = src; src = dst; dst = t;
    }
    if (tid < 512) {
        const int incl = src[tid];
        const int excl = incl - v;
        const int node = (b << BSHIFT) + tid;
        if (node < NN) rng[node] = make_int2(base + excl, base + incl);
        dst[tid] = excl;
    }
    __syncthreads();
    for (int e = tid; e < cnt; e += 1024) {
        const int2 sw = srcdw[base + e];
        const int dl = (sw.x >> 17) & 511;
        const int pos = atomicAdd(&dst[dl], 1);
        edges2[base + pos] = make_int2(sw.x & 0x1FFFF, sw.y);
    }
}

// ---------------- CSR SpMM: 8 nodes/wave, 8 edges per gather instr ----------------
__global__ __launch_bounds__(256) void spmm_csr(const __hip_bfloat16* __restrict__ feat,
                                                const int2* __restrict__ rng,
                                                const int2* __restrict__ edges2,
                                                const float* __restrict__ b,
                                                float* __restrict__ out) {
    const int nwg = gridDim.x;
    const int q = nwg >> 3, rr = nwg & 7;
    const int xcd = blockIdx.x & 7;
    const int sub = blockIdx.x >> 3;
    const int swz = (xcd < rr ? xcd * (q + 1) : rr * (q + 1) + (xcd - rr) * q) + sub;
    const int w = threadIdx.x >> 6;
    const int lane = threadIdx.x & 63;
    const int n0 = (swz * 4 + w) * NPW;
    const int p = lane >> 3;
    const int f8 = lane & 7;
    const float4 bv0 = *(const float4*)(b + f8 * 8);
    const float4 bv1 = *(const float4*)(b + f8 * 8 + 4);
    const int2 r8 = rng[n0 + f8];
#define FMA8(G, WV)                                            \
    a0 = fmaf(__uint_as_float((G).x << 16), (WV), a0);         \
    a1 = fmaf(__uint_as_float((G).x & 0xffff0000u), (WV), a1); \
    a2 = fmaf(__uint_as_float((G).y << 16), (WV), a2);         \
    a3 = fmaf(__uint_as_float((G).y & 0xffff0000u), (WV), a3); \
    a4 = fmaf(__uint_as_float((G).z << 16), (WV), a4);         \
    a5 = fmaf(__uint_as_float((G).z & 0xffff0000u), (WV), a5); \
    a6 = fmaf(__uint_as_float((G).w << 16), (WV), a6);         \
    a7 = fmaf(__uint_as_float((G).w & 0xffff0000u), (WV), a7);
#define RED(A) A += __shfl_xor(A, 8, 64); A += __shfl_xor(A, 16, 64); A += __shfl_xor(A, 32, 64);
#pragma unroll 1
    for (int nn = 0; nn < NPW; ++nn) {
        const int n = n0 + nn;
        const int beg = __shfl(r8.x, nn, 64);
        const int end = __shfl(r8.y, nn, 64);
        float a0 = 0.f, a1 = 0.f, a2 = 0.f, a3 = 0.f;
        float a4 = 0.f, a5 = 0.f, a6 = 0.f, a7 = 0.f;
        int i = beg;
        for (; i + 15 < end; i += 16) {
            const int2 e0 = edges2[i + p];
            const int2 e1 = edges2[i + 8 + p];
            const uint4 g0 = *(const uint4*)(feat + (size_t)e0.x * 64 + f8 * 8);
            const uint4 g1 = *(const uint4*)(feat + (size_t)e1.x * 64 + f8 * 8);
            const float w0 = __int_as_float(e0.y), w1 = __int_as_float(e1.y);
            FMA8(g0, w0) FMA8(g1, w1)
        }
        for (; i < end; i += 8) {
            const int idx = i + p;
            const int2 e = edges2[idx];
            const float wv = (idx < end) ? __int_as_float(e.y) : 0.f;
            const uint4 g = *(const uint4*)(feat + (size_t)(e.x & 0x1FFFF) * 64 + f8 * 8);
            FMA8(g, wv)
        }
        RED(a0) RED(a1) RED(a2) RED(a3) RED(a4) RED(a5) RED(a6) RED(a7)
        if (p == 0) {
            float4 o0, o1;
            o0.x = fmaxf(a0 + bv0.x, 0.f);
            o0.y = fmaxf(a1 + bv0.y, 0.f);
            o0.z = fmaxf(a2 + bv0.z, 0.f);
            o0.w = fmaxf(a3 + bv0.w, 0.f);
            o1.x = fmaxf(a4 + bv1.x, 0.f);
            o1.y = fmaxf(a5 + bv1.y, 0.f);
            o1.z = fmaxf(a6 + bv1.z, 0.f);
            o1.w = fmaxf(a7 + bv1.w, 0.f);
            *(float4*)(out + (size_t)n * 64 + f8 * 8) = o0;
            *(float4*)(out + (size_t)n * 64 + f8 * 8 + 4) = o1;
        }
    }
#undef FMA8
#undef RED
}

// ============ head: 128 rows x 40 cols per block, register-tiled ============
__global__ __launch_bounds__(256) void head_tile(const float* __restrict__ h2,
                                                 const float* __restrict__ Wl,
                                                 const float* __restrict__ bl,
                                                 float* __restrict__ logits,
                                                 float* __restrict__ logp) {
    __shared__ float Wt[40 * 68];
    __shared__ float Xs[HROWS * 68];
    __shared__ float bs[40];
    const int tid = threadIdx.x;
    const int row0 = blockIdx.x * HROWS;
    for (int i = tid; i < 64 * 40; i += 256) {
        const int k = i / 40, c = i - k * 40;
        Wt[c * 68 + k] = Wl[i];
    }
    if (tid < 40) bs[tid] = bl[tid];
    for (int i = tid; i < HROWS * 16; i += 256) {
        const int r = i >> 4, kq = i & 15;
        const int row = row0 + r;
        float4 v = make_float4(0.f, 0.f, 0.f, 0.f);
        if (row < NN) v = *(const float4*)(h2 + (size_t)row * 64 + kq * 4);
        *(float4*)(&Xs[r * 68 + kq * 4]) = v;
    }
    __syncthreads();
    const int tcol = tid & 3;
    const int trow = tid >> 2;
    float acc[2][10] = {};
    const float* xb0 = &Xs[trow * 68];
    const float* xb1 = &Xs[(trow + 64) * 68];
    const float* wb = &Wt[(tcol * 10) * 68];
    for (int k = 0; k < 64; k += 4) {
        const float4 x0 = *(const float4*)(xb0 + k);
        const float4 x1 = *(const float4*)(xb1 + k);
#pragma unroll
        for (int c = 0; c < 10; ++c) {
            const float4 wv = *(const float4*)(wb + c * 68 + k);
            acc[0][c] = fmaf(x0.x, wv.x, acc[0][c]);
            acc[0][c] = fmaf(x0.y, wv.y, acc[0][c]);
            acc[0][c] = fmaf(x0.z, wv.z, acc[0][c]);
            acc[0][c] = fmaf(x0.w, wv.w, acc[0][c]);
            acc[1][c] = fmaf(x1.x, wv.x, acc[1][c]);
            acc[1][c] = fmaf(x1.y, wv.y, acc[1][c]);
            acc[1][c] = fmaf(x1.z, wv.z, acc[1][c]);
            acc[1][c] = fmaf(x1.w, wv.w, acc[1][c]);
        }
    }
    float bv[10];
#pragma unroll
    for (int c = 0; c < 10; ++c) bv[c] = bs[tcol * 10 + c];
#pragma unroll
    for (int r = 0; r < 2; ++r) {
        const int row = row0 + trow + r * 64;
#pragma unroll
        for (int c = 0; c < 10; ++c) acc[r][c] += bv[c];
        float m = acc[r][0];
#pragma unroll
        for (int c = 1; c < 10; ++c) m = fmaxf(m, acc[r][c]);
        m = fmaxf(m, __shfl_xor(m, 1, 64));
        m = fmaxf(m, __shfl_xor(m, 2, 64));
        float s = 0.f;
#pragma unroll
        for (int c = 0; c < 10; ++c) s += expf(acc[r][c] - m);
        s += __shfl_xor(s, 1, 64);
        s += __shfl_xor(s, 2, 64);
        const float lse = logf(s) + m;
        if (row < NN) {
            float* lg = logits + (size_t)row * 40 + tcol * 10;
            float* lp = logp   + (size_t)row * 40 + tcol * 10;
#pragma unroll
            for (int c = 0; c < 10; c += 2) {
                *(float2*)(lg + c) = make_float2(acc[r][c], acc[r][c + 1]);
                *(float2*)(lp + c) = make_float2(acc[r][c] - lse, acc[r][c + 1] - lse);
            }
        }
    }
}

extern "C" void kernel_launch(void* const* d_in, const int* in_sizes, int n_in,
                              void* d_out, int out_size, void* d_ws, size_t ws_size,
                              hipStream_t stream) {
    const float* x  = (const float*)d_in[0];
    const int*   es = (const int*)  d_in[1];
    const int*   ed = (const int*)  d_in[2];
    const float* ew = (const float*)d_in[3];
    const float* W1 = (const float*)d_in[4];
    const float* b1 = (const float*)d_in[5];
    const float* W2 = (const float*)d_in[6];
    const float* b2 = (const float*)d_in[7];
    const float* Wl = (const float*)d_in[8];
    const float* bl = (const float*)d_in[9];

    float* out    = (float*)d_out;
    float* logp   = out;                          // [N,40]
    float* h1     = logp + (size_t)NN * 40;       // [N,64]
    float* h2     = h1   + (size_t)NN * 64;       // [N,64]
    float* logits = h2   + (size_t)NN * 64;       // [N,40]

    // workspace: NO overlay (ws0 written concurrently with srcdw in the fused kernel)
    char* wsb = (char*)d_ws;
    const size_t regionA = (size_t)NBUCK * CAP * 8;                   // 16.06 MB
    int2* srcdw = (int2*)wsb;                                         // [NBUCK*CAP]
    int2* edges2 = (int2*)(wsb + regionA);                            // [NBUCK*CAP]
    int2* rng    = (int2*)((char*)edges2 + regionA);                  // [NN] 800 KB
    int*  bcur   = (int*)((char*)rng + (size_t)NN * 8);               // [NBUCK]
    __hip_bfloat16* ws0 = (__hip_bfloat16*)((char*)bcur + 4096);      // [N,64] bf16 12.8 MB

    const int gemmGrid = (NN + 127) / 128;        // 782
    const int spmmGrid = NN / (4 * NPW);          // 3125

    // ---- [gemm1 ∥ CSR binning] then per-bucket finalize ----
    hipMemsetAsync(bcur, 0, (size_t)NBUCK * 4, stream);
    gemm1_bin<<<G1GRID + BINGRID, 256, 0, stream>>>(x, W1, ws0, es, ed, ew, bcur, srcdw);
    bucket_csr<<<NBUCK, 1024, 0, stream>>>(srcdw, bcur, rng, edges2);

    // ---- layer 1 aggregate ----
    spmm_csr<<<spmmGrid, 256, 0, stream>>>(ws0, rng, edges2, b1, h1);

    // ---- layer 2 ----
    gemm2_mfma<<<gemmGrid, 256, 0, stream>>>(h1, W2, ws0);
    spmm_csr<<<spmmGrid, 256, 0, stream>>>(ws0, rng, edges2, b2, h2);

    // ---- head ----
    head_tile<<<(NN + HROWS - 1) / HROWS, 256, 0, stream>>>(h2, Wl, bl, logits, logp);
}

// Round 20
// 179.272 us; speedup vs baseline: 1.0435x; 1.0271x over previous
//
#include <hip/hip_runtime.h>
#include <hip/hip_bf16.h>
#include <math.h>

#define NN 100000
#define NE 1600000
#define BSHIFT 9
#define NBUCK ((NN + (1 << BSHIFT) - 1) >> BSHIFT)   // 196
#define CAP 10240
#define BCHUNK 4096
#define BINGRID ((NE + BCHUNK - 1) / BCHUNK)         // 391
#define G1GRID ((NN + 127) / 128)                    // 782
#define HROWS 128
#define NPW 8

typedef __attribute__((ext_vector_type(8))) short bf16x8;
typedef __attribute__((ext_vector_type(4))) float f32x4;

static __device__ inline unsigned short f2b(float f) {
    __hip_bfloat16 b = __float2bfloat16(f);
    return *reinterpret_cast<unsigned short*>(&b);
}

static __device__ inline bf16x8 pack8(float4 fa, float4 fb) {
    union { bf16x8 v; unsigned u[4]; } pk;
    pk.u[0] = (unsigned)f2b(fa.x) | ((unsigned)f2b(fa.y) << 16);
    pk.u[1] = (unsigned)f2b(fa.z) | ((unsigned)f2b(fa.w) << 16);
    pk.u[2] = (unsigned)f2b(fb.x) | ((unsigned)f2b(fb.y) << 16);
    pk.u[3] = (unsigned)f2b(fb.z) | ((unsigned)f2b(fb.w) << 16);
    return pk.v;
}

// ============ FUSED: gemm1 (MFMA, blocks 0..G1GRID) ∥ bin_edges (rest) ============
// bin: BCHUNK=4096 (21-edge write runs, write-amp ~1.4x) with NO d[] register
// cache — ed[] reloaded in the scatter pass (L2-hot) to keep VGPR/occupancy high.
__global__ __launch_bounds__(256) void gemm1_bin(const float* __restrict__ x,
                                                 const float* __restrict__ W,
                                                 __hip_bfloat16* __restrict__ out,
                                                 const int* __restrict__ es,
                                                 const int* __restrict__ ed,
                                                 const float* __restrict__ ew,
                                                 int* __restrict__ bcur,
                                                 int2* __restrict__ srcdw) {
    __shared__ __align__(16) unsigned short Wt[64 * 136];    // 17408 B
    const int tid = threadIdx.x;
    if (blockIdx.x < G1GRID) {
        // ---------------- gemm1: x[N,128] @ W1[128,64] -> bf16 ----------------
        const int row0 = blockIdx.x * 128;
        for (int i = tid; i < 64 * 64; i += 256) {
            const int n = i & 63, kp = i >> 6;
            const unsigned pack = (unsigned)f2b(W[(2 * kp) * 64 + n]) |
                                  ((unsigned)f2b(W[(2 * kp + 1) * 64 + n]) << 16);
            *(unsigned*)&Wt[n * 136 + 2 * kp] = pack;
        }
        __syncthreads();
        const int l = tid & 63;
        const int wid = tid >> 6;
        const int m = l & 15, g = l >> 4;
        const int wr0 = wid * 32;
        f32x4 acc[2][4];
#pragma unroll
        for (int rt = 0; rt < 2; ++rt)
#pragma unroll
            for (int ct = 0; ct < 4; ++ct) acc[rt][ct] = 0;
#pragma unroll
        for (int ks = 0; ks < 4; ++ks) {
            bf16x8 a[2], b[4];
#pragma unroll
            for (int rt = 0; rt < 2; ++rt) {
                const int row = row0 + wr0 + rt * 16 + m;
                float4 fa = make_float4(0.f, 0.f, 0.f, 0.f), fb = fa;
                if (row < NN) {
                    const float* xr = x + (size_t)row * 128 + ks * 32 + g * 8;
                    fa = *(const float4*)xr;
                    fb = *(const float4*)(xr + 4);
                }
                a[rt] = pack8(fa, fb);
            }
#pragma unroll
            for (int ct = 0; ct < 4; ++ct)
                b[ct] = *(const bf16x8*)&Wt[(ct * 16 + m) * 136 + ks * 32 + g * 8];
#pragma unroll
            for (int rt = 0; rt < 2; ++rt)
#pragma unroll
                for (int ct = 0; ct < 4; ++ct)
                    acc[rt][ct] = __builtin_amdgcn_mfma_f32_16x16x32_bf16(a[rt], b[ct], acc[rt][ct], 0, 0, 0);
        }
#pragma unroll
        for (int rt = 0; rt < 2; ++rt)
#pragma unroll
            for (int ct = 0; ct < 4; ++ct)
#pragma unroll
                for (int j = 0; j < 4; ++j) {
                    const int r = row0 + wr0 + rt * 16 + g * 4 + j;
                    if (r < NN)
                        out[(size_t)r * 64 + ct * 16 + m] = __float2bfloat16(acc[rt][ct][j]);
                }
    } else {
        // ---------------- bin_edges: 16 edges/thread, no register cache ----------------
        int* hist = (int*)Wt;
        int* base = hist + NBUCK;
        const int e0 = (blockIdx.x - G1GRID) * BCHUNK;
        for (int i = tid; i < NBUCK; i += 256) hist[i] = 0;
        __syncthreads();
#pragma unroll 4
        for (int j = 0; j < 16; ++j) {
            const int e = e0 + j * 256 + tid;
            if (e < NE) atomicAdd(&hist[ed[e] >> BSHIFT], 1);
        }
        __syncthreads();
        for (int i = tid; i < NBUCK; i += 256)
            base[i] = i * CAP + atomicAdd(&bcur[i], hist[i]);   // bcur holds relative counts
        __syncthreads();
        for (int i = tid; i < NBUCK; i += 256) hist[i] = 0;
        __syncthreads();
#pragma unroll 4
        for (int j = 0; j < 16; ++j) {
            const int e = e0 + j * 256 + tid;
            if (e < NE) {
                const int dd = ed[e];                           // L2-hot reload
                const int bb = dd >> BSHIFT;
                const int l2 = atomicAdd(&hist[bb], 1);
                srcdw[base[bb] + l2] =
                    make_int2(es[e] | ((dd & 511) << 17), __float_as_int(ew[e]));
            }
        }
    }
}

// ============ GEMM2 (MFMA): h[N,64] @ W2[64,64] -> out_bf16[N,64] ============
__global__ __launch_bounds__(256) void gemm2_mfma(const float* __restrict__ h,
                                                  const float* __restrict__ W,
                                                  __hip_bfloat16* __restrict__ out) {
    __shared__ __align__(16) unsigned short Wt[64 * 72];     // 9216 B
    const int tid = threadIdx.x;
    const int row0 = blockIdx.x * 128;
    for (int i = tid; i < 64 * 32; i += 256) {
        const int n = i & 63, kp = i >> 6;
        const unsigned pack = (unsigned)f2b(W[(2 * kp) * 64 + n]) |
                              ((unsigned)f2b(W[(2 * kp + 1) * 64 + n]) << 16);
        *(unsigned*)&Wt[n * 72 + 2 * kp] = pack;
    }
    __syncthreads();
    const int l = tid & 63;
    const int wid = tid >> 6;
    const int m = l & 15, g = l >> 4;
    const int wr0 = wid * 32;
    f32x4 acc[2][4];
#pragma unroll
    for (int rt = 0; rt < 2; ++rt)
#pragma unroll
        for (int ct = 0; ct < 4; ++ct) acc[rt][ct] = 0;
#pragma unroll
    for (int ks = 0; ks < 2; ++ks) {
        bf16x8 a[2], b[4];
#pragma unroll
        for (int rt = 0; rt < 2; ++rt) {
            const int row = row0 + wr0 + rt * 16 + m;
            float4 fa = make_float4(0.f, 0.f, 0.f, 0.f), fb = fa;
            if (row < NN) {
                const float* hr = h + (size_t)row * 64 + ks * 32 + g * 8;
                fa = *(const float4*)hr;
                fb = *(const float4*)(hr + 4);
            }
            a[rt] = pack8(fa, fb);
        }
#pragma unroll
        for (int ct = 0; ct < 4; ++ct)
            b[ct] = *(const bf16x8*)&Wt[(ct * 16 + m) * 72 + ks * 32 + g * 8];
#pragma unroll
        for (int rt = 0; rt < 2; ++rt)
#pragma unroll
            for (int ct = 0; ct < 4; ++ct)
                acc[rt][ct] = __builtin_amdgcn_mfma_f32_16x16x32_bf16(a[rt], b[ct], acc[rt][ct], 0, 0, 0);
    }
#pragma unroll
    for (int rt = 0; rt < 2; ++rt)
#pragma unroll
        for (int ct = 0; ct < 4; ++ct)
#pragma unroll
            for (int j = 0; j < 4; ++j) {
                const int r = row0 + wr0 + rt * 16 + g * 4 + j;
                if (r < NN)
                    out[(size_t)r * 64 + ct * 16 + m] = __float2bfloat16(acc[rt][ct][j]);
            }
}

// ---------------- per-bucket CSR finalize (1024 threads) ----------------
__global__ __launch_bounds__(1024) void bucket_csr(const int2* __restrict__ srcdw,
                                                   const int* __restrict__ bcur,
                                                   int2* __restrict__ rng,
                                                   int2* __restrict__ edges2) {
    __shared__ int A[512], B2[512];
    const int tid = threadIdx.x;
    const int b = blockIdx.x;
    const int base = b * CAP;
    const int cnt = bcur[b];                   // relative count
    if (tid < 512) A[tid] = 0;
    __syncthreads();
    for (int e = tid; e < cnt; e += 1024)
        atomicAdd(&A[(srcdw[base + e].x >> 17) & 511], 1);
    __syncthreads();
    const int v = (tid < 512) ? A[tid] : 0;
    int* src = A;
    int* dst = B2;
    for (int d = 1; d < 512; d <<= 1) {
        if (tid < 512) dst[tid] = src[tid] + ((tid >= d) ? src[tid - d] : 0);
        __syncthreads();
        int* t = src; src = dst; dst = t;
    }
    if (tid < 512) {
        const int incl = src[tid];
        const int excl = incl - v;
        const int node = (b << BSHIFT) + tid;
        if (node < NN) rng[node] = make_int2(base + excl, base + incl);
        dst[tid] = excl;
    }
    __syncthreads();
    for (int e = tid; e < cnt; e += 1024) {
        const int2 sw = srcdw[base + e];
        const int dl = (sw.x >> 17) & 511;
        const int pos = atomicAdd(&dst[dl], 1);
        edges2[base + pos] = make_int2(sw.x & 0x1FFFF, sw.y);
    }
}

// ---------------- CSR SpMM: 8 nodes/wave, 8 edges per gather instr ----------------
__global__ __launch_bounds__(256) void spmm_csr(const __hip_bfloat16* __restrict__ feat,
                                                const int2* __restrict__ rng,
                                                const int2* __restrict__ edges2,
                                                const float* __restrict__ b,
                                                float* __restrict__ out) {
    const int nwg = gridDim.x;
    const int q = nwg >> 3, rr = nwg & 7;
    const int xcd = blockIdx.x & 7;
    const int sub = blockIdx.x >> 3;
    const int swz = (xcd < rr ? xcd * (q + 1) : rr * (q + 1) + (xcd - rr) * q) + sub;
    const int w = threadIdx.x >> 6;
    const int lane = threadIdx.x & 63;
    const int n0 = (swz * 4 + w) * NPW;
    const int p = lane >> 3;
    const int f8 = lane & 7;
    const float4 bv0 = *(const float4*)(b + f8 * 8);
    const float4 bv1 = *(const float4*)(b + f8 * 8 + 4);
    const int2 r8 = rng[n0 + f8];
#define FMA8(G, WV)                                            \
    a0 = fmaf(__uint_as_float((G).x << 16), (WV), a0);         \
    a1 = fmaf(__uint_as_float((G).x & 0xffff0000u), (WV), a1); \
    a2 = fmaf(__uint_as_float((G).y << 16), (WV), a2);         \
    a3 = fmaf(__uint_as_float((G).y & 0xffff0000u), (WV), a3); \
    a4 = fmaf(__uint_as_float((G).z << 16), (WV), a4);         \
    a5 = fmaf(__uint_as_float((G).z & 0xffff0000u), (WV), a5); \
    a6 = fmaf(__uint_as_float((G).w << 16), (WV), a6);         \
    a7 = fmaf(__uint_as_float((G).w & 0xffff0000u), (WV), a7);
#define RED(A) A += __shfl_xor(A, 8, 64); A += __shfl_xor(A, 16, 64); A += __shfl_xor(A, 32, 64);
#pragma unroll 1
    for (int nn = 0; nn < NPW; ++nn) {
        const int n = n0 + nn;
        const int beg = __shfl(r8.x, nn, 64);
        const int end = __shfl(r8.y, nn, 64);
        float a0 = 0.f, a1 = 0.f, a2 = 0.f, a3 = 0.f;
        float a4 = 0.f, a5 = 0.f, a6 = 0.f, a7 = 0.f;
        int i = beg;
        for (; i + 15 < end; i += 16) {
            const int2 e0 = edges2[i + p];
            const int2 e1 = edges2[i + 8 + p];
            const uint4 g0 = *(const uint4*)(feat + (size_t)e0.x * 64 + f8 * 8);
            const uint4 g1 = *(const uint4*)(feat + (size_t)e1.x * 64 + f8 * 8);
            const float w0 = __int_as_float(e0.y), w1 = __int_as_float(e1.y);
            FMA8(g0, w0) FMA8(g1, w1)
        }
        for (; i < end; i += 8) {
            const int idx = i + p;
            const int2 e = edges2[idx];
            const float wv = (idx < end) ? __int_as_float(e.y) : 0.f;
            const uint4 g = *(const uint4*)(feat + (size_t)(e.x & 0x1FFFF) * 64 + f8 * 8);
            FMA8(g, wv)
        }
        RED(a0) RED(a1) RED(a2) RED(a3) RED(a4) RED(a5) RED(a6) RED(a7)
        if (p == 0) {
            float4 o0, o1;
            o0.x = fmaxf(a0 + bv0.x, 0.f);
            o0.y = fmaxf(a1 + bv0.y, 0.f);
            o0.z = fmaxf(a2 + bv0.z, 0.f);
            o0.w = fmaxf(a3 + bv0.w, 0.f);
            o1.x = fmaxf(a4 + bv1.x, 0.f);
            o1.y = fmaxf(a5 + bv1.y, 0.f);
            o1.z = fmaxf(a6 + bv1.z, 0.f);
            o1.w = fmaxf(a7 + bv1.w, 0.f);
            *(float4*)(out + (size_t)n * 64 + f8 * 8) = o0;
            *(float4*)(out + (size_t)n * 64 + f8 * 8 + 4) = o1;
        }
    }
#undef FMA8
#undef RED
}

// ============ head: 128 rows x 40 cols per block, register-tiled ============
__global__ __launch_bounds__(256) void head_tile(const float* __restrict__ h2,
                                                 const float* __restrict__ Wl,
                                                 const float* __restrict__ bl,
                                                 float* __restrict__ logits,
                                                 float* __restrict__ logp) {
    __shared__ float Wt[40 * 68];
    __shared__ float Xs[HROWS * 68];
    __shared__ float bs[40];
    const int tid = threadIdx.x;
    const int row0 = blockIdx.x * HROWS;
    for (int i = tid; i < 64 * 40; i += 256) {
        const int k = i / 40, c = i - k * 40;
        Wt[c * 68 + k] = Wl[i];
    }
    if (tid < 40) bs[tid] = bl[tid];
    for (int i = tid; i < HROWS * 16; i += 256) {
        const int r = i >> 4, kq = i & 15;
        const int row = row0 + r;
        float4 v = make_float4(0.f, 0.f, 0.f, 0.f);
        if (row < NN) v = *(const float4*)(h2 + (size_t)row * 64 + kq * 4);
        *(float4*)(&Xs[r * 68 + kq * 4]) = v;
    }
    __syncthreads();
    const int tcol = tid & 3;
    const int trow = tid >> 2;
    float acc[2][10] = {};
    const float* xb0 = &Xs[trow * 68];
    const float* xb1 = &Xs[(trow + 64) * 68];
    const float* wb = &Wt[(tcol * 10) * 68];
    for (int k = 0; k < 64; k += 4) {
        const float4 x0 = *(const float4*)(xb0 + k);
        const float4 x1 = *(const float4*)(xb1 + k);
#pragma unroll
        for (int c = 0; c < 10; ++c) {
            const float4 wv = *(const float4*)(wb + c * 68 + k);
            acc[0][c] = fmaf(x0.x, wv.x, acc[0][c]);
            acc[0][c] = fmaf(x0.y, wv.y, acc[0][c]);
            acc[0][c] = fmaf(x0.z, wv.z, acc[0][c]);
            acc[0][c] = fmaf(x0.w, wv.w, acc[0][c]);
            acc[1][c] = fmaf(x1.x, wv.x, acc[1][c]);
            acc[1][c] = fmaf(x1.y, wv.y, acc[1][c]);
            acc[1][c] = fmaf(x1.z, wv.z, acc[1][c]);
            acc[1][c] = fmaf(x1.w, wv.w, acc[1][c]);
        }
    }
    float bv[10];
#pragma unroll
    for (int c = 0; c < 10; ++c) bv[c] = bs[tcol * 10 + c];
#pragma unroll
    for (int r = 0; r < 2; ++r) {
        const int row = row0 + trow + r * 64;
#pragma unroll
        for (int c = 0; c < 10; ++c) acc[r][c] += bv[c];
        float m = acc[r][0];
#pragma unroll
        for (int c = 1; c < 10; ++c) m = fmaxf(m, acc[r][c]);
        m = fmaxf(m, __shfl_xor(m, 1, 64));
        m = fmaxf(m, __shfl_xor(m, 2, 64));
        float s = 0.f;
#pragma unroll
        for (int c = 0; c < 10; ++c) s += expf(acc[r][c] - m);
        s += __shfl_xor(s, 1, 64);
        s += __shfl_xor(s, 2, 64);
        const float lse = logf(s) + m;
        if (row < NN) {
            float* lg = logits + (size_t)row * 40 + tcol * 10;
            float* lp = logp   + (size_t)row * 40 + tcol * 10;
#pragma unroll
            for (int c = 0; c < 10; c += 2) {
                *(float2*)(lg + c) = make_float2(acc[r][c], acc[r][c + 1]);
                *(float2*)(lp + c) = make_float2(acc[r][c] - lse, acc[r][c + 1] - lse);
            }
        }
    }
}

extern "C" void kernel_launch(void* const* d_in, const int* in_sizes, int n_in,
                              void* d_out, int out_size, void* d_ws, size_t ws_size,
                              hipStream_t stream) {
    const float* x  = (const float*)d_in[0];
    const int*   es = (const int*)  d_in[1];
    const int*   ed = (const int*)  d_in[2];
    const float* ew = (const float*)d_in[3];
    const float* W1 = (const float*)d_in[4];
    const float* b1 = (const float*)d_in[5];
    const float* W2 = (const float*)d_in[6];
    const float* b2 = (const float*)d_in[7];
    const float* Wl = (const float*)d_in[8];
    const float* bl = (const float*)d_in[9];

    float* out    = (float*)d_out;
    float* logp   = out;                          // [N,40]
    float* h1     = logp + (size_t)NN * 40;       // [N,64]
    float* h2     = h1   + (size_t)NN * 64;       // [N,64]
    float* logits = h2   + (size_t)NN * 64;       // [N,40]

    // workspace: NO overlay (ws0 written concurrently with srcdw in the fused kernel)
    char* wsb = (char*)d_ws;
    const size_t regionA = (size_t)NBUCK * CAP * 8;                   // 16.06 MB
    int2* srcdw = (int2*)wsb;                                         // [NBUCK*CAP]
    int2* edges2 = (int2*)(wsb + regionA);                            // [NBUCK*CAP]
    int2* rng    = (int2*)((char*)edges2 + regionA);                  // [NN] 800 KB
    int*  bcur   = (int*)((char*)rng + (size_t)NN * 8);               // [NBUCK]
    __hip_bfloat16* ws0 = (__hip_bfloat16*)((char*)bcur + 4096);      // [N,64] bf16 12.8 MB

    const int gemmGrid = (NN + 127) / 128;        // 782
    const int spmmGrid = NN / (4 * NPW);          // 3125

    // ---- [gemm1 ∥ CSR binning] then per-bucket finalize ----
    hipMemsetAsync(bcur, 0, (size_t)NBUCK * 4, stream);
    gemm1_bin<<<G1GRID + BINGRID, 256, 0, stream>>>(x, W1, ws0, es, ed, ew, bcur, srcdw);
    bucket_csr<<<NBUCK, 1024, 0, stream>>>(srcdw, bcur, rng, edges2);

    // ---- layer 1 aggregate ----
    spmm_csr<<<spmmGrid, 256, 0, stream>>>(ws0, rng, edges2, b1, h1);

    // ---- layer 2 ----
    gemm2_mfma<<<gemmGrid, 256, 0, stream>>>(h1, W2, ws0);
    spmm_csr<<<spmmGrid, 256, 0, stream>>>(ws0, rng, edges2, b2, h2);

    // ---- head ----
    head_tile<<<(NN + HROWS - 1) / HROWS, 256, 0, stream>>>(h2, Wl, bl, logits, logp);
}